// Round 4
// baseline (1983.954 us; speedup 1.0000x reference)
//
#include <hip/hip_runtime.h>
#include <stdint.h>

#define B_ 2
#define NX_ 2048
#define NLQ_ 64
#define T_ 2112
#define DIN_ 768
#define DOUT_ 768
#define NH_ 12
#define HD_ 64

#define QSZ_ ((size_t)3244032)   // B*NH*T*HD floats (= B*T*DOUT)
#define HALF_U 53526528u         // NH*T*T (per-batch flat count)

// dropout scheme: 0 = partitionable, out = bits1 (REFUTED round 3: absmax 2.2e-2)
//                 1 = jax threefry_partitionable 32-bit: out = bits1 ^ bits2   <-- current
//                 2 = legacy split-iota pairing (out[i<H]=y0, out[i>=H]=y1 of tf(i, i+H))
#define DROP_SCHEME 1

__device__ __forceinline__ uint32_t rotl_(uint32_t x, uint32_t r) {
  return (x << r) | (x >> (32u - r));
}

// Threefry-2x32, 20 rounds, key = (0, 42)  [jax.random.key(42) -> (seed>>32, seed&mask)]
__device__ __forceinline__ uint2 threefry_(uint32_t x0, uint32_t x1) {
  const uint32_t ks0 = 0u, ks1 = 42u;
  const uint32_t ks2 = 0x1BD11BDAu ^ ks0 ^ ks1;
  x0 += ks0; x1 += ks1;
#define TFR_(r) { x0 += x1; x1 = rotl_(x1, (r)); x1 ^= x0; }
  TFR_(13) TFR_(15) TFR_(26) TFR_(6)
  x0 += ks1; x1 += ks2 + 1u;
  TFR_(17) TFR_(29) TFR_(16) TFR_(24)
  x0 += ks2; x1 += ks0 + 2u;
  TFR_(13) TFR_(15) TFR_(26) TFR_(6)
  x0 += ks0; x1 += ks1 + 3u;
  TFR_(17) TFR_(29) TFR_(16) TFR_(24)
  x0 += ks1; x1 += ks2 + 4u;
  TFR_(13) TFR_(15) TFR_(26) TFR_(6)
  x0 += ks2; x1 += ks0 + 5u;
#undef TFR_
  return make_uint2(x0, x1);
}

__device__ __forceinline__ float u01_(uint32_t bits) {
  // jax _uniform: bitcast(bits>>9 | 0x3f800000) - 1.0
  return __uint_as_float((bits >> 9) | 0x3f800000u) - 1.0f;
}

// uniform for element with per-batch flat index n0 = (h*T + i)*T + j, batch b
__device__ __forceinline__ float drop_u_(uint32_t n0, int b) {
#if DROP_SCHEME == 0
  const uint32_t n = (uint32_t)b * HALF_U + n0;     // global flat < 2^32, hi word = 0
  const uint2 y = threefry_(0u, n);
  return u01_(y.x);
#elif DROP_SCHEME == 1
  const uint32_t n = (uint32_t)b * HALF_U + n0;     // counts = iota(u64): hi=0, lo=n
  const uint2 y = threefry_(0u, n);
  return u01_(y.x ^ y.y);                           // 32-bit partitionable: bits1 ^ bits2
#else
  const uint2 y = threefry_(n0, n0 + HALF_U);       // pair (n0, n0+H): y0 -> b=0, y1 -> b=1
  return u01_(b ? y.y : y.x);
#endif
}

// ---------------- QKV projection: [B*T,768] @ W -> [b,h,t,hd] ----------------
__global__ __launch_bounds__(256) void qkv_kernel(
    const float* __restrict__ xg, const float* __restrict__ lqg,
    const float* __restrict__ Wq, const float* __restrict__ Wk,
    const float* __restrict__ Wv, float* __restrict__ ws) {
  __shared__ float As[16][68];
  __shared__ float Bs[16][68];
  const int tid = threadIdx.x;
  const int m0 = blockIdx.x << 6;
  const int h  = blockIdx.y;                 // output col tile = h*64
  const int w  = blockIdx.z;
  const float* Wm = (w == 0) ? Wq : (w == 1) ? Wk : Wv;
  float* outb = ws + (size_t)w * QSZ_;

  const int ar = tid >> 2;
  const int ak = (tid & 3) << 2;
  const float* arow;
  {
    const int m = m0 + ar;
    const int bb = m / T_;
    const int tt = m - bb * T_;
    arow = (tt < NX_) ? (xg + ((size_t)bb * NX_ + tt) * DIN_)
                      : (lqg + ((size_t)bb * NLQ_ + (tt - NX_)) * DIN_);
  }
  const int bkr = tid >> 4;
  const int bnc = (tid & 15) << 2;
  const float* wp = Wm + (size_t)bkr * DOUT_ + (h << 6) + bnc;

  const int ty = tid >> 4, tx = tid & 15;
  float acc[4][4] = {};
  for (int k0 = 0; k0 < DIN_; k0 += 16) {
    const float4 av = *(const float4*)(arow + k0 + ak);
    const float4 bv = *(const float4*)(wp + (size_t)k0 * DOUT_);
    __syncthreads();
    As[ak + 0][ar] = av.x; As[ak + 1][ar] = av.y;
    As[ak + 2][ar] = av.z; As[ak + 3][ar] = av.w;
    *(float4*)&Bs[bkr][bnc] = bv;
    __syncthreads();
#pragma unroll
    for (int kk = 0; kk < 16; ++kk) {
      const float4 a  = *(const float4*)&As[kk][ty << 2];
      const float4 bq = *(const float4*)&Bs[kk][tx << 2];
      acc[0][0] += a.x * bq.x; acc[0][1] += a.x * bq.y; acc[0][2] += a.x * bq.z; acc[0][3] += a.x * bq.w;
      acc[1][0] += a.y * bq.x; acc[1][1] += a.y * bq.y; acc[1][2] += a.y * bq.z; acc[1][3] += a.y * bq.w;
      acc[2][0] += a.z * bq.x; acc[2][1] += a.z * bq.y; acc[2][2] += a.z * bq.z; acc[2][3] += a.z * bq.w;
      acc[3][0] += a.w * bq.x; acc[3][1] += a.w * bq.y; acc[3][2] += a.w * bq.z; acc[3][3] += a.w * bq.w;
    }
  }
#pragma unroll
  for (int i = 0; i < 4; ++i) {
    const int m = m0 + (ty << 2) + i;
    const int bb = m / T_;
    const int tt = m - bb * T_;
    float* dst = outb + ((size_t)(bb * NH_ + h) * T_ + tt) * HD_ + (tx << 2);
    dst[0] = acc[i][0]; dst[1] = acc[i][1]; dst[2] = acc[i][2]; dst[3] = acc[i][3];
  }
}

// ---------------- flash attention + exact jax-threefry dropout ----------------
__global__ __launch_bounds__(256) void attn_kernel(
    const float* __restrict__ Qb, const float* __restrict__ Kb,
    const float* __restrict__ Vb, float* __restrict__ ctx) {
  __shared__ float Qs[32][65];
  __shared__ float Ks[64][65];
  __shared__ float Vs[64][65];
  __shared__ float Ps[32][65];
  const int tid = threadIdx.x;
  const int q0 = blockIdx.x << 5;
  const int h  = blockIdx.y;
  const int b  = blockIdx.z;
  const size_t hb = (size_t)(b * NH_ + h) * T_;

  {
    const int lr = tid >> 3;
    const int lc = (tid & 7) << 3;
    const float4 v0 = *(const float4*)(Qb + (hb + q0 + lr) * HD_ + lc);
    const float4 v1 = *(const float4*)(Qb + (hb + q0 + lr) * HD_ + lc + 4);
    Qs[lr][lc + 0] = v0.x; Qs[lr][lc + 1] = v0.y; Qs[lr][lc + 2] = v0.z; Qs[lr][lc + 3] = v0.w;
    Qs[lr][lc + 4] = v1.x; Qs[lr][lc + 5] = v1.y; Qs[lr][lc + 6] = v1.z; Qs[lr][lc + 7] = v1.w;
  }
  const int r  = tid >> 3;    // q-row within tile (8 threads per row)
  const int l8 = tid & 7;
  const int jb = l8 << 3;     // this thread's 8 score cols / 8 output dims
  const int qi = q0 + r;
  float m_i = -1e30f, l_i = 0.0f;
  float acc[8] = {0, 0, 0, 0, 0, 0, 0, 0};

  const int kvr = tid >> 2;
  const int kvc = (tid & 3) << 4;
  const uint32_t nrow = (uint32_t)(h * T_ + qi) * (uint32_t)T_;   // per-batch flat row base

  for (int kt = 0; kt < T_; kt += 64) {
    __syncthreads();
    {
      const float* ksrc = Kb + (hb + kt + kvr) * HD_ + kvc;
      const float* vsrc = Vb + (hb + kt + kvr) * HD_ + kvc;
#pragma unroll
      for (int q4 = 0; q4 < 16; q4 += 4) {
        const float4 kv = *(const float4*)(ksrc + q4);
        const float4 vv = *(const float4*)(vsrc + q4);
        Ks[kvr][kvc + q4 + 0] = kv.x; Ks[kvr][kvc + q4 + 1] = kv.y;
        Ks[kvr][kvc + q4 + 2] = kv.z; Ks[kvr][kvc + q4 + 3] = kv.w;
        Vs[kvr][kvc + q4 + 0] = vv.x; Vs[kvr][kvc + q4 + 1] = vv.y;
        Vs[kvr][kvc + q4 + 2] = vv.z; Vs[kvr][kvc + q4 + 3] = vv.w;
      }
    }
    __syncthreads();

    float s[8] = {0, 0, 0, 0, 0, 0, 0, 0};
    for (int d = 0; d < 64; ++d) {
      const float qv = Qs[r][d];
#pragma unroll
      for (int jj = 0; jj < 8; ++jj) s[jj] += qv * Ks[jb + jj][d];
    }
#pragma unroll
    for (int jj = 0; jj < 8; ++jj) s[jj] *= 0.125f;   // 1/sqrt(64)

    float tm = s[0];
#pragma unroll
    for (int jj = 1; jj < 8; ++jj) tm = fmaxf(tm, s[jj]);
    tm = fmaxf(tm, __shfl_xor(tm, 1));
    tm = fmaxf(tm, __shfl_xor(tm, 2));
    tm = fmaxf(tm, __shfl_xor(tm, 4));
    const float m_new = fmaxf(m_i, tm);
    const float alpha = __expf(m_i - m_new);
    float p[8], ls = 0.0f;
#pragma unroll
    for (int jj = 0; jj < 8; ++jj) { p[jj] = __expf(s[jj] - m_new); ls += p[jj]; }
    ls += __shfl_xor(ls, 1);
    ls += __shfl_xor(ls, 2);
    ls += __shfl_xor(ls, 4);
    l_i = l_i * alpha + ls;    // denominator: UNmasked (softmax first, dropout after)
    m_i = m_new;
#pragma unroll
    for (int dd = 0; dd < 8; ++dd) acc[dd] *= alpha;

    // dropout mask on numerator only; keep_p uniform over each 8-col group (2048 % 8 == 0)
    const float kp = ((qi < NX_) && (kt + jb < NX_)) ? 0.9f : 0.8f;
    const uint32_t nb = nrow + (uint32_t)(kt + jb);
#pragma unroll
    for (int jj = 0; jj < 8; ++jj) {
      const float u = drop_u_(nb + (uint32_t)jj, b);
      Ps[r][jb + jj] = (u < kp) ? p[jj] : 0.0f;
    }
    __syncthreads();

#pragma unroll 8
    for (int j = 0; j < 64; ++j) {
      const float pj = Ps[r][j];
#pragma unroll
      for (int dd = 0; dd < 8; ++dd) acc[dd] += pj * Vs[j][jb + dd];
    }
  }

  // ctx = (scale / l) * acc ; scale exactly as reference computes it in f64 -> f32
  const float inv = (float)(4460544.0 / (4194304.0 * 0.9 + 266240.0 * 0.8)) / l_i;
  float* dst = ctx + ((size_t)(b * T_ + q0 + r)) * DOUT_ + (h << 6) + jb;
#pragma unroll
  for (int dd = 0; dd < 8; ++dd) dst[dd] = acc[dd] * inv;
}

// ---------------- output projection + bias ----------------
__global__ __launch_bounds__(256) void oproj_kernel(
    const float* __restrict__ ctxm, const float* __restrict__ Wo,
    const float* __restrict__ bo, float* __restrict__ out) {
  __shared__ float As[16][68];
  __shared__ float Bs[16][68];
  const int tid = threadIdx.x;
  const int m0 = blockIdx.x << 6;
  const int n0 = blockIdx.y << 6;
  const int ar = tid >> 2;
  const int ak = (tid & 3) << 2;
  const float* arow = ctxm + (size_t)(m0 + ar) * DIN_;
  const int bkr = tid >> 4;
  const int bnc = (tid & 15) << 2;
  const float* wp = Wo + (size_t)bkr * DOUT_ + n0 + bnc;
  const int ty = tid >> 4, tx = tid & 15;
  float acc[4][4] = {};
  for (int k0 = 0; k0 < DIN_; k0 += 16) {
    const float4 av = *(const float4*)(arow + k0 + ak);
    const float4 bv = *(const float4*)(wp + (size_t)k0 * DOUT_);
    __syncthreads();
    As[ak + 0][ar] = av.x; As[ak + 1][ar] = av.y;
    As[ak + 2][ar] = av.z; As[ak + 3][ar] = av.w;
    *(float4*)&Bs[bkr][bnc] = bv;
    __syncthreads();
#pragma unroll
    for (int kk = 0; kk < 16; ++kk) {
      const float4 a  = *(const float4*)&As[kk][ty << 2];
      const float4 bq = *(const float4*)&Bs[kk][tx << 2];
      acc[0][0] += a.x * bq.x; acc[0][1] += a.x * bq.y; acc[0][2] += a.x * bq.z; acc[0][3] += a.x * bq.w;
      acc[1][0] += a.y * bq.x; acc[1][1] += a.y * bq.y; acc[1][2] += a.y * bq.z; acc[1][3] += a.y * bq.w;
      acc[2][0] += a.z * bq.x; acc[2][1] += a.z * bq.y; acc[2][2] += a.z * bq.z; acc[2][3] += a.z * bq.w;
      acc[3][0] += a.w * bq.x; acc[3][1] += a.w * bq.y; acc[3][2] += a.w * bq.z; acc[3][3] += a.w * bq.w;
    }
  }
  const float4 bias = *(const float4*)(bo + n0 + (tx << 2));
#pragma unroll
  for (int i = 0; i < 4; ++i) {
    float* dst = out + (size_t)(m0 + (ty << 2) + i) * DOUT_ + n0 + (tx << 2);
    dst[0] = acc[i][0] + bias.x; dst[1] = acc[i][1] + bias.y;
    dst[2] = acc[i][2] + bias.z; dst[3] = acc[i][3] + bias.w;
  }
}

extern "C" void kernel_launch(void* const* d_in, const int* in_sizes, int n_in,
                              void* d_out, int out_size, void* d_ws, size_t ws_size,
                              hipStream_t stream) {
  (void)in_sizes; (void)n_in; (void)out_size; (void)ws_size;
  const float* x  = (const float*)d_in[0];
  const float* lq = (const float*)d_in[1];
  const float* Wq = (const float*)d_in[2];
  const float* Wk = (const float*)d_in[3];
  const float* Wv = (const float*)d_in[4];
  const float* Wo = (const float*)d_in[5];
  const float* bo = (const float*)d_in[6];
  float* ws = (float*)d_ws;
  float* Qb = ws;
  float* Kb = ws + QSZ_;
  float* Vb = ws + 2 * QSZ_;
  float* Cb = ws + 3 * QSZ_;
  qkv_kernel<<<dim3(66, 12, 3), dim3(256), 0, stream>>>(x, lq, Wq, Wk, Wv, ws);
  attn_kernel<<<dim3(66, NH_, B_), dim3(256), 0, stream>>>(Qb, Kb, Vb, Cb);
  oproj_kernel<<<dim3(66, 12, 1), dim3(256), 0, stream>>>(Cb, Wo, bo, (float*)d_out);
}

// Round 5
// 665.695 us; speedup vs baseline: 2.9803x; 2.9803x over previous
//
#include <hip/hip_runtime.h>
#include <stdint.h>

#define B_ 2
#define NX_ 2048
#define NLQ_ 64
#define T_ 2112
#define DIN_ 768
#define DOUT_ 768
#define NH_ 12
#define HD_ 64

#define QSZ_ ((size_t)3244032)   // B*NH*T*HD elements
#define HALF_U 53526528u         // NH*T*T (per-batch flat count)
#define SCALE_ ((float)(4460544.0 / (4194304.0 * 0.9 + 266240.0 * 0.8)))

typedef __attribute__((ext_vector_type(8))) short bf16x8;
typedef __attribute__((ext_vector_type(4))) float f32x4;
typedef unsigned int uint32;

__device__ __forceinline__ uint32 rotl_(uint32 x, uint32 r) {
  return (x << r) | (x >> (32u - r));
}

// Threefry-2x32, 20 rounds, key = (0, 42); jax partitionable 32-bit: out = y.x ^ y.y
__device__ __forceinline__ uint2 threefry_(uint32 x0, uint32 x1) {
  const uint32 ks0 = 0u, ks1 = 42u;
  const uint32 ks2 = 0x1BD11BDAu ^ ks0 ^ ks1;
  x0 += ks0; x1 += ks1;
#define TFR_(r) { x0 += x1; x1 = rotl_(x1, (r)); x1 ^= x0; }
  TFR_(13) TFR_(15) TFR_(26) TFR_(6)
  x0 += ks1; x1 += ks2 + 1u;
  TFR_(17) TFR_(29) TFR_(16) TFR_(24)
  x0 += ks2; x1 += ks0 + 2u;
  TFR_(13) TFR_(15) TFR_(26) TFR_(6)
  x0 += ks0; x1 += ks1 + 3u;
  TFR_(17) TFR_(29) TFR_(16) TFR_(24)
  x0 += ks1; x1 += ks2 + 4u;
  TFR_(13) TFR_(15) TFR_(26) TFR_(6)
  x0 += ks2; x1 += ks0 + 5u;
#undef TFR_
  return make_uint2(x0, x1);
}

__device__ __forceinline__ float u01_(uint32 bits) {
  return __uint_as_float((bits >> 9) | 0x3f800000u) - 1.0f;
}

__device__ __forceinline__ unsigned short f2b_(float f) {  // f32 -> bf16 RNE
  const uint32 u = __float_as_uint(f);
  return (unsigned short)((u + 0x7FFFu + ((u >> 16) & 1u)) >> 16);
}

// ---------- QKV projection: f32 GEMM, epilogue emits bf16 Q(*0.125),K,[V transposed] ----------
__global__ __launch_bounds__(256) void qkv_kernel(
    const float* __restrict__ xg, const float* __restrict__ lqg,
    const float* __restrict__ Wq, const float* __restrict__ Wk,
    const float* __restrict__ Wv,
    unsigned short* __restrict__ Qh, unsigned short* __restrict__ Kh,
    unsigned short* __restrict__ Vth) {
  __shared__ float As[16][68];
  __shared__ float Bs[16][68];
  const int tid = threadIdx.x;
  const int m0 = blockIdx.x << 6;
  const int h  = blockIdx.y;
  const int w  = blockIdx.z;
  const float* Wm = (w == 0) ? Wq : (w == 1) ? Wk : Wv;

  const int ar = tid >> 2;
  const int ak = (tid & 3) << 2;
  const float* arow;
  {
    const int m = m0 + ar;
    const int bb = m / T_;
    const int tt = m - bb * T_;
    arow = (tt < NX_) ? (xg + ((size_t)bb * NX_ + tt) * DIN_)
                      : (lqg + ((size_t)bb * NLQ_ + (tt - NX_)) * DIN_);
  }
  const int bkr = tid >> 4;
  const int bnc = (tid & 15) << 2;
  const float* wp = Wm + (size_t)bkr * DOUT_ + (h << 6) + bnc;

  const int ty = tid >> 4, tx = tid & 15;
  float acc[4][4] = {};
  for (int k0 = 0; k0 < DIN_; k0 += 16) {
    const float4 av = *(const float4*)(arow + k0 + ak);
    const float4 bv = *(const float4*)(wp + (size_t)k0 * DOUT_);
    __syncthreads();
    As[ak + 0][ar] = av.x; As[ak + 1][ar] = av.y;
    As[ak + 2][ar] = av.z; As[ak + 3][ar] = av.w;
    *(float4*)&Bs[bkr][bnc] = bv;
    __syncthreads();
#pragma unroll
    for (int kk = 0; kk < 16; ++kk) {
      const float4 a  = *(const float4*)&As[kk][ty << 2];
      const float4 bq = *(const float4*)&Bs[kk][tx << 2];
      acc[0][0] += a.x * bq.x; acc[0][1] += a.x * bq.y; acc[0][2] += a.x * bq.z; acc[0][3] += a.x * bq.w;
      acc[1][0] += a.y * bq.x; acc[1][1] += a.y * bq.y; acc[1][2] += a.y * bq.z; acc[1][3] += a.y * bq.w;
      acc[2][0] += a.z * bq.x; acc[2][1] += a.z * bq.y; acc[2][2] += a.z * bq.z; acc[2][3] += a.z * bq.w;
      acc[3][0] += a.w * bq.x; acc[3][1] += a.w * bq.y; acc[3][2] += a.w * bq.z; acc[3][3] += a.w * bq.w;
    }
  }
  // m0 tiles are 64-aligned and 2112 % 64 == 0 -> batch uniform per block
  const int bb2 = m0 / T_;
  const int tt0 = m0 - bb2 * T_ + (ty << 2);
  if (w == 0) {
#pragma unroll
    for (int i = 0; i < 4; ++i) {
      ushort4 o;
      o.x = f2b_(acc[i][0] * 0.125f); o.y = f2b_(acc[i][1] * 0.125f);
      o.z = f2b_(acc[i][2] * 0.125f); o.w = f2b_(acc[i][3] * 0.125f);
      *(ushort4*)(Qh + ((size_t)(bb2 * NH_ + h) * T_ + tt0 + i) * HD_ + (tx << 2)) = o;
    }
  } else if (w == 1) {
#pragma unroll
    for (int i = 0; i < 4; ++i) {
      ushort4 o;
      o.x = f2b_(acc[i][0]); o.y = f2b_(acc[i][1]);
      o.z = f2b_(acc[i][2]); o.w = f2b_(acc[i][3]);
      *(ushort4*)(Kh + ((size_t)(bb2 * NH_ + h) * T_ + tt0 + i) * HD_ + (tx << 2)) = o;
    }
  } else {
    // V transposed: Vt[(b*NH+h)*64 + hd][t]
#pragma unroll
    for (int j = 0; j < 4; ++j) {
      ushort4 o;
      o.x = f2b_(acc[0][j]); o.y = f2b_(acc[1][j]);
      o.z = f2b_(acc[2][j]); o.w = f2b_(acc[3][j]);
      *(ushort4*)(Vth + ((size_t)(bb2 * NH_ + h) * HD_ + (tx << 2) + j) * T_ + tt0) = o;
    }
  }
}

// ---------- MFMA flash attention + exact jax-threefry dropout ----------
// block: 256 thr (4 waves), 64 q-rows; wave w owns q rows [q0+16w, q0+16w+16)
__global__ __launch_bounds__(256) void attn_kernel(
    const unsigned short* __restrict__ Qh, const unsigned short* __restrict__ Kh,
    const unsigned short* __restrict__ Vth, float* __restrict__ ctx) {
  __shared__ unsigned short KsU[4096];          // K tile [64 kv][64 hd], XOR-swizzled
  __shared__ unsigned short VsU[4096];          // V^T tile [64 hd][64 kv], XOR-swizzled
  __shared__ unsigned short PsU[4 * 16 * 72];   // per-wave P [16 q][72 kv-pad]

  const int tid = threadIdx.x;
  const int w   = tid >> 6;
  const int lane = tid & 63;
  const int c = lane & 15;      // MFMA col index / q-local on Ps read
  const int g = lane >> 4;      // k-chunk group
  const int q0 = blockIdx.x << 6;
  const int h  = blockIdx.y;
  const int b  = blockIdx.z;
  const size_t hbT = (size_t)(b * NH_ + h) * T_;
  const size_t vbase = (size_t)(b * NH_ + h) * HD_;

  // Q A-fragments (row = q-local = c, k = 32s + 8g + j)
  bf16x8 aq0, aq1;
  {
    const unsigned short* qrow = Qh + (hbT + q0 + 16 * w + c) * HD_ + (g << 3);
    aq0 = *(const bf16x8*)(qrow);
    aq1 = *(const bf16x8*)(qrow + 32);
  }

  f32x4 ca0 = {0.f, 0.f, 0.f, 0.f}, ca1 = ca0, ca2 = ca0, ca3 = ca0;  // ctx acc, hd n-tiles
  float lacc[4] = {0.f, 0.f, 0.f, 0.f};                               // partial denominators

  uint32 baseI[4];
#pragma unroll
  for (int i = 0; i < 4; ++i)
    baseI[i] = (uint32)b * HALF_U +
               (uint32)(h * T_ + q0 + 16 * w + 4 * g + i) * (uint32)T_;

  const int psE = w * 1152;          // Ps element base (16*72 per wave)
  const int psB = w * 2304;          // Ps byte base
  const int swz = (c & 7) << 4;      // read-side XOR swizzle

  for (int kt = 0; kt < T_; kt += 64) {
    // ---- stage K tile and V^T tile (bf16, XOR-swizzled rows) ----
#pragma unroll
    for (int ii = 0; ii < 2; ++ii) {
      const int seg  = tid + (ii << 8);
      const int srow = seg >> 3;
      const int sc   = (seg & 7) << 3;  // element offset within row
      const uint4 kv4 = *(const uint4*)(Kh + (hbT + kt + srow) * HD_ + sc);
      *(uint4*)((char*)KsU + srow * 128 + ((sc * 2) ^ ((srow & 7) << 4))) = kv4;
      const uint4 vv4 = *(const uint4*)(Vth + (vbase + srow) * T_ + kt + sc);
      *(uint4*)((char*)VsU + srow * 128 + ((sc * 2) ^ ((srow & 7) << 4))) = vv4;
    }
    __syncthreads();

    // ---- QK^T: S[q 16][kv 64] per wave ----
    f32x4 sa0 = {0.f, 0.f, 0.f, 0.f}, sa1 = sa0, sa2 = sa0, sa3 = sa0;
#pragma unroll
    for (int s = 0; s < 2; ++s) {
      const int off = ((s << 6) + (g << 4)) ^ swz;
      const bf16x8 bk0 = *(const bf16x8*)((const char*)KsU + (c     ) * 128 + off);
      const bf16x8 bk1 = *(const bf16x8*)((const char*)KsU + (c + 16) * 128 + off);
      const bf16x8 bk2 = *(const bf16x8*)((const char*)KsU + (c + 32) * 128 + off);
      const bf16x8 bk3 = *(const bf16x8*)((const char*)KsU + (c + 48) * 128 + off);
      const bf16x8 aqs = s ? aq1 : aq0;
      sa0 = __builtin_amdgcn_mfma_f32_16x16x32_bf16(aqs, bk0, sa0, 0, 0, 0);
      sa1 = __builtin_amdgcn_mfma_f32_16x16x32_bf16(aqs, bk1, sa1, 0, 0, 0);
      sa2 = __builtin_amdgcn_mfma_f32_16x16x32_bf16(aqs, bk2, sa2, 0, 0, 0);
      sa3 = __builtin_amdgcn_mfma_f32_16x16x32_bf16(aqs, bk3, sa3, 0, 0, 0);
    }

    // ---- exp + threefry dropout, pack masked P to LDS (no max-sub: |s| <~ 2) ----
    const float kp = (q0 < NX_ && kt < NX_) ? 0.9f : 0.8f;
#pragma unroll
    for (int n = 0; n < 4; ++n) {
      const f32x4 sv = (n == 0) ? sa0 : (n == 1) ? sa1 : (n == 2) ? sa2 : sa3;
      const uint32 colIdx = (uint32)(kt + 16 * n + c);
#pragma unroll
      for (int i = 0; i < 4; ++i) {
        const float pe = __expf(sv[i]);
        lacc[i] += pe;
        const uint2 y = threefry_(0u, baseI[i] + colIdx);
        const float u = u01_(y.x ^ y.y);
        PsU[psE + (4 * g + i) * 72 + 16 * n + c] = f2b_((u < kp) ? pe : 0.0f);
      }
    }
    __syncthreads();   // Ps write->read ordering (and Ks read done before next stage)

    // ---- PV: ctx += P @ V ----
    const bf16x8 ap0 = *(const bf16x8*)((const char*)PsU + psB + c * 144 + (g << 4));
    const bf16x8 ap1 = *(const bf16x8*)((const char*)PsU + psB + c * 144 + 64 + (g << 4));
#pragma unroll
    for (int s = 0; s < 2; ++s) {
      const int off = ((s << 6) + (g << 4)) ^ swz;
      const bf16x8 bv0 = *(const bf16x8*)((const char*)VsU + (c     ) * 128 + off);
      const bf16x8 bv1 = *(const bf16x8*)((const char*)VsU + (c + 16) * 128 + off);
      const bf16x8 bv2 = *(const bf16x8*)((const char*)VsU + (c + 32) * 128 + off);
      const bf16x8 bv3 = *(const bf16x8*)((const char*)VsU + (c + 48) * 128 + off);
      const bf16x8 aps = s ? ap1 : ap0;
      ca0 = __builtin_amdgcn_mfma_f32_16x16x32_bf16(aps, bv0, ca0, 0, 0, 0);
      ca1 = __builtin_amdgcn_mfma_f32_16x16x32_bf16(aps, bv1, ca1, 0, 0, 0);
      ca2 = __builtin_amdgcn_mfma_f32_16x16x32_bf16(aps, bv2, ca2, 0, 0, 0);
      ca3 = __builtin_amdgcn_mfma_f32_16x16x32_bf16(aps, bv3, ca3, 0, 0, 0);
    }
    __syncthreads();   // all waves done with Vt/Ks before next stage
  }

  // ---- epilogue: reduce denominators across 16-lane group, scale, store ----
#pragma unroll
  for (int i = 0; i < 4; ++i) {
    float li = lacc[i];
    li += __shfl_xor(li, 1);
    li += __shfl_xor(li, 2);
    li += __shfl_xor(li, 4);
    li += __shfl_xor(li, 8);
    const float inv = SCALE_ / li;
    float* dst = ctx + (size_t)(b * T_ + q0 + 16 * w + 4 * g + i) * DOUT_ + (h << 6) + c;
    dst[0]  = ca0[i] * inv;
    dst[16] = ca1[i] * inv;
    dst[32] = ca2[i] * inv;
    dst[48] = ca3[i] * inv;
  }
}

// ---------- output projection + bias (f32) ----------
__global__ __launch_bounds__(256) void oproj_kernel(
    const float* __restrict__ ctxm, const float* __restrict__ Wo,
    const float* __restrict__ bo, float* __restrict__ out) {
  __shared__ float As[16][68];
  __shared__ float Bs[16][68];
  const int tid = threadIdx.x;
  const int m0 = blockIdx.x << 6;
  const int n0 = blockIdx.y << 6;
  const int ar = tid >> 2;
  const int ak = (tid & 3) << 2;
  const float* arow = ctxm + (size_t)(m0 + ar) * DIN_;
  const int bkr = tid >> 4;
  const int bnc = (tid & 15) << 2;
  const float* wp = Wo + (size_t)bkr * DOUT_ + n0 + bnc;
  const int ty = tid >> 4, tx = tid & 15;
  float acc[4][4] = {};
  for (int k0 = 0; k0 < DIN_; k0 += 16) {
    const float4 av = *(const float4*)(arow + k0 + ak);
    const float4 bv = *(const float4*)(wp + (size_t)k0 * DOUT_);
    __syncthreads();
    As[ak + 0][ar] = av.x; As[ak + 1][ar] = av.y;
    As[ak + 2][ar] = av.z; As[ak + 3][ar] = av.w;
    *(float4*)&Bs[bkr][bnc] = bv;
    __syncthreads();
#pragma unroll
    for (int kk = 0; kk < 16; ++kk) {
      const float4 a  = *(const float4*)&As[kk][ty << 2];
      const float4 bq = *(const float4*)&Bs[kk][tx << 2];
      acc[0][0] += a.x * bq.x; acc[0][1] += a.x * bq.y; acc[0][2] += a.x * bq.z; acc[0][3] += a.x * bq.w;
      acc[1][0] += a.y * bq.x; acc[1][1] += a.y * bq.y; acc[1][2] += a.y * bq.z; acc[1][3] += a.y * bq.w;
      acc[2][0] += a.z * bq.x; acc[2][1] += a.z * bq.y; acc[2][2] += a.z * bq.z; acc[2][3] += a.z * bq.w;
      acc[3][0] += a.w * bq.x; acc[3][1] += a.w * bq.y; acc[3][2] += a.w * bq.z; acc[3][3] += a.w * bq.w;
    }
  }
  const float4 bias = *(const float4*)(bo + n0 + (tx << 2));
#pragma unroll
  for (int i = 0; i < 4; ++i) {
    float* dst = out + (size_t)(m0 + (ty << 2) + i) * DOUT_ + n0 + (tx << 2);
    dst[0] = acc[i][0] + bias.x; dst[1] = acc[i][1] + bias.y;
    dst[2] = acc[i][2] + bias.z; dst[3] = acc[i][3] + bias.w;
  }
}

extern "C" void kernel_launch(void* const* d_in, const int* in_sizes, int n_in,
                              void* d_out, int out_size, void* d_ws, size_t ws_size,
                              hipStream_t stream) {
  (void)in_sizes; (void)n_in; (void)out_size; (void)ws_size;
  const float* x  = (const float*)d_in[0];
  const float* lq = (const float*)d_in[1];
  const float* Wq = (const float*)d_in[2];
  const float* Wk = (const float*)d_in[3];
  const float* Wv = (const float*)d_in[4];
  const float* Wo = (const float*)d_in[5];
  const float* bo = (const float*)d_in[6];
  unsigned short* Qh  = (unsigned short*)d_ws;
  unsigned short* Kh  = Qh + QSZ_;
  unsigned short* Vth = Kh + QSZ_;
  float* Cb = (float*)(Vth + QSZ_);
  qkv_kernel<<<dim3(66, 12, 3), dim3(256), 0, stream>>>(x, lq, Wq, Wk, Wv, Qh, Kh, Vth);
  attn_kernel<<<dim3(33, NH_, B_), dim3(256), 0, stream>>>(Qh, Kh, Vth, Cb);
  oproj_kernel<<<dim3(66, 12, 1), dim3(256), 0, stream>>>(Cb, Wo, bo, (float*)d_out);
}

// Round 6
// 472.333 us; speedup vs baseline: 4.2003x; 1.4094x over previous
//
#include <hip/hip_runtime.h>
#include <stdint.h>

#define B_ 2
#define NX_ 2048
#define NLQ_ 64
#define T_ 2112
#define DIN_ 768
#define DOUT_ 768
#define NH_ 12
#define HD_ 64

#define QSZ_ ((size_t)3244032)   // B*NH*T*HD elements
#define HALF_U 53526528u         // NH*T*T (per-batch flat count)
#define SCALE_ ((float)(4460544.0 / (4194304.0 * 0.9 + 266240.0 * 0.8)))
#define WPR_ 66                  // mask words per dropout row (2112/32)
#define MWPB_ 1408u              // mask words per qkv block (3345408 / 2376)
// integer-domain dropout compare (exact): u = (bits>>9)*2^-23;
// 0.9f = 15099494/2^24 -> u<0.9f <=> bits>>9 < 7549747
// 0.8f = 13421773/2^24 -> u<0.8f <=> bits>>9 < 6710887
#define K_X_ 7549747u
#define K_LQ_ 6710887u

typedef __attribute__((ext_vector_type(8))) short bf16x8;
typedef __attribute__((ext_vector_type(4))) float f32x4;
typedef unsigned int uint32;

__device__ __forceinline__ uint32 rotl_(uint32 x, uint32 r) {
  return (x << r) | (x >> (32u - r));
}

// Threefry-2x32, 20 rounds, key=(0,42); jax partitionable 32-bit: out = y.x ^ y.y
__device__ __forceinline__ uint2 threefry_(uint32 x0, uint32 x1) {
  const uint32 ks0 = 0u, ks1 = 42u;
  const uint32 ks2 = 0x1BD11BDAu ^ ks0 ^ ks1;
  x0 += ks0; x1 += ks1;
#define TFR_(r) { x0 += x1; x1 = rotl_(x1, (r)); x1 ^= x0; }
  TFR_(13) TFR_(15) TFR_(26) TFR_(6)
  x0 += ks1; x1 += ks2 + 1u;
  TFR_(17) TFR_(29) TFR_(16) TFR_(24)
  x0 += ks2; x1 += ks0 + 2u;
  TFR_(13) TFR_(15) TFR_(26) TFR_(6)
  x0 += ks0; x1 += ks1 + 3u;
  TFR_(17) TFR_(29) TFR_(16) TFR_(24)
  x0 += ks1; x1 += ks2 + 4u;
  TFR_(13) TFR_(15) TFR_(26) TFR_(6)
  x0 += ks2; x1 += ks0 + 5u;
#undef TFR_
  return make_uint2(x0, x1);
}

__device__ __forceinline__ unsigned short f2b_(float f) {  // f32 -> bf16 RNE
  const uint32 u = __float_as_uint(f);
  return (unsigned short)((u + 0x7FFFu + ((u >> 16) & 1u)) >> 16);
}
__device__ __forceinline__ uint32 pack2_(float lo, float hi) {
  return (uint32)f2b_(lo) | ((uint32)f2b_(hi) << 16);
}

// ---------- prep: Wt[mat][n][k] bf16 = transpose(W[k][n]) for q,k,v,o ----------
__global__ __launch_bounds__(256) void prep_kernel(
    const float* __restrict__ Wq, const float* __restrict__ Wk,
    const float* __restrict__ Wv, const float* __restrict__ Wo,
    unsigned short* __restrict__ Wt) {
  __shared__ float Tf[64][65];
  const int tid = threadIdx.x;
  const int k0 = blockIdx.x << 6;
  const int n0 = blockIdx.y << 6;
  const int mat = blockIdx.z;
  const float* Wm = (mat == 0) ? Wq : (mat == 1) ? Wk : (mat == 2) ? Wv : Wo;
  const int r = tid >> 2;
  const int cch = (tid & 3) << 4;
  const float* src = Wm + (size_t)(k0 + r) * DOUT_ + n0 + cch;
#pragma unroll
  for (int j = 0; j < 4; ++j) {
    const float4 v = *(const float4*)(src + 4 * j);
    Tf[r][cch + 4 * j + 0] = v.x; Tf[r][cch + 4 * j + 1] = v.y;
    Tf[r][cch + 4 * j + 2] = v.z; Tf[r][cch + 4 * j + 3] = v.w;
  }
  __syncthreads();
  float f[16];
#pragma unroll
  for (int j = 0; j < 16; ++j) f[j] = Tf[cch + j][r];
  uint4 o0, o1;
  o0.x = pack2_(f[0], f[1]);  o0.y = pack2_(f[2], f[3]);
  o0.z = pack2_(f[4], f[5]);  o0.w = pack2_(f[6], f[7]);
  o1.x = pack2_(f[8], f[9]);  o1.y = pack2_(f[10], f[11]);
  o1.z = pack2_(f[12], f[13]); o1.w = pack2_(f[14], f[15]);
  unsigned short* dst = Wt + ((size_t)mat * DOUT_ + n0 + r) * DIN_ + k0 + cch;
  *(uint4*)dst = o0;
  *(uint4*)(dst + 8) = o1;
}

// ---------- qkv: bf16 MFMA GEMM (Q*0.125, K, V-transposed) + threefry mask phase ----------
__global__ __launch_bounds__(256) void qkv_kernel(
    const float* __restrict__ xg, const float* __restrict__ lqg,
    const unsigned short* __restrict__ Wt,
    unsigned short* __restrict__ Qh, unsigned short* __restrict__ Kh,
    unsigned short* __restrict__ Vth, uint32* __restrict__ Mask) {
  __shared__ unsigned short AsB[4096];   // [64 m][64 k] bf16, XOR-swizzled rows
  __shared__ unsigned short BsB[4096];   // [64 n][64 k] bf16 (=W^T tile)
  const int tid = threadIdx.x;
  const int w = tid >> 6;
  const int lane = tid & 63;
  const int c = lane & 15;
  const int g = lane >> 4;
  const int m0 = blockIdx.x << 6;
  const int wsel = blockIdx.y / NH_;
  const int h = blockIdx.y % NH_;

  const int ar = tid >> 2;
  const int kpart = (tid & 3) << 4;
  const float* arow;
  {
    const int m = m0 + ar;
    const int bb = m / T_;
    const int tt = m - bb * T_;
    arow = (tt < NX_) ? (xg + ((size_t)bb * NX_ + tt) * DIN_)
                      : (lqg + ((size_t)bb * NLQ_ + (tt - NX_)) * DIN_);
  }
  const unsigned short* brow = Wt + ((size_t)wsel * DOUT_ + h * HD_ + ar) * DIN_;
  const int wrA = ar * 128;
  const int swzS = (ar & 7) << 4;
  const int swzF = (c & 7) << 4;

  f32x4 ac0 = {0.f, 0.f, 0.f, 0.f}, ac1 = ac0, ac2 = ac0, ac3 = ac0;

  for (int k0 = 0; k0 < DIN_; k0 += 64) {
    const float4 a0 = *(const float4*)(arow + k0 + kpart);
    const float4 a1 = *(const float4*)(arow + k0 + kpart + 4);
    const float4 a2 = *(const float4*)(arow + k0 + kpart + 8);
    const float4 a3 = *(const float4*)(arow + k0 + kpart + 12);
    const uint4 b01 = *(const uint4*)(brow + k0 + kpart);
    const uint4 b23 = *(const uint4*)(brow + k0 + kpart + 8);
    uint4 pa0, pa1;
    pa0.x = pack2_(a0.x, a0.y); pa0.y = pack2_(a0.z, a0.w);
    pa0.z = pack2_(a1.x, a1.y); pa0.w = pack2_(a1.z, a1.w);
    pa1.x = pack2_(a2.x, a2.y); pa1.y = pack2_(a2.z, a2.w);
    pa1.z = pack2_(a3.x, a3.y); pa1.w = pack2_(a3.z, a3.w);
    __syncthreads();
    *(uint4*)((char*)AsB + wrA + ((kpart * 2) ^ swzS)) = pa0;
    *(uint4*)((char*)AsB + wrA + ((kpart * 2 + 16) ^ swzS)) = pa1;
    *(uint4*)((char*)BsB + wrA + ((kpart * 2) ^ swzS)) = b01;
    *(uint4*)((char*)BsB + wrA + ((kpart * 2 + 16) ^ swzS)) = b23;
    __syncthreads();
#pragma unroll
    for (int s = 0; s < 2; ++s) {
      const int off = ((s << 6) | (g << 4)) ^ swzF;
      const bf16x8 af = *(const bf16x8*)((const char*)AsB + (16 * w + c) * 128 + off);
      const bf16x8 b0 = *(const bf16x8*)((const char*)BsB + (c) * 128 + off);
      const bf16x8 b1 = *(const bf16x8*)((const char*)BsB + (c + 16) * 128 + off);
      const bf16x8 b2 = *(const bf16x8*)((const char*)BsB + (c + 32) * 128 + off);
      const bf16x8 b3 = *(const bf16x8*)((const char*)BsB + (c + 48) * 128 + off);
      ac0 = __builtin_amdgcn_mfma_f32_16x16x32_bf16(af, b0, ac0, 0, 0, 0);
      ac1 = __builtin_amdgcn_mfma_f32_16x16x32_bf16(af, b1, ac1, 0, 0, 0);
      ac2 = __builtin_amdgcn_mfma_f32_16x16x32_bf16(af, b2, ac2, 0, 0, 0);
      ac3 = __builtin_amdgcn_mfma_f32_16x16x32_bf16(af, b3, ac3, 0, 0, 0);
    }
  }

  const int bb2 = m0 / T_;
  const int tb = m0 - bb2 * T_;
  const size_t rowBase = (size_t)(bb2 * NH_ + h) * T_;
  if (wsel == 0) {
#pragma unroll
    for (int i = 0; i < 4; ++i) {
      const size_t rr = (rowBase + tb + 16 * w + 4 * g + i) * HD_ + c;
      Qh[rr +  0] = f2b_(ac0[i] * 0.125f);
      Qh[rr + 16] = f2b_(ac1[i] * 0.125f);
      Qh[rr + 32] = f2b_(ac2[i] * 0.125f);
      Qh[rr + 48] = f2b_(ac3[i] * 0.125f);
    }
  } else if (wsel == 1) {
#pragma unroll
    for (int i = 0; i < 4; ++i) {
      const size_t rr = (rowBase + tb + 16 * w + 4 * g + i) * HD_ + c;
      Kh[rr +  0] = f2b_(ac0[i]);
      Kh[rr + 16] = f2b_(ac1[i]);
      Kh[rr + 32] = f2b_(ac2[i]);
      Kh[rr + 48] = f2b_(ac3[i]);
    }
  } else {
    __syncthreads();   // all frag reads done; reuse AsB as transpose buffer
#pragma unroll
    for (int i = 0; i < 4; ++i) {
      const int col2 = (16 * w + 4 * g + i) * 2;
      *(unsigned short*)((char*)AsB + (c)      * 128 + (col2 ^ ((c & 7) << 4))) = f2b_(ac0[i]);
      *(unsigned short*)((char*)AsB + (c + 16) * 128 + (col2 ^ ((c & 7) << 4))) = f2b_(ac1[i]);
      *(unsigned short*)((char*)AsB + (c + 32) * 128 + (col2 ^ ((c & 7) << 4))) = f2b_(ac2[i]);
      *(unsigned short*)((char*)AsB + (c + 48) * 128 + (col2 ^ ((c & 7) << 4))) = f2b_(ac3[i]);
    }
    __syncthreads();
    const int hd = tid >> 2;
    const int tch = (tid & 3) << 4;
    const uint4 v0 = *(const uint4*)((const char*)AsB + hd * 128 + ((tch * 2) ^ ((hd & 7) << 4)));
    const uint4 v1 = *(const uint4*)((const char*)AsB + hd * 128 + ((tch * 2 + 16) ^ ((hd & 7) << 4)));
    unsigned short* dst = Vth + ((size_t)(bb2 * NH_ + h) * HD_ + hd) * T_ + tb + tch;
    *(uint4*)dst = v0;
    *(uint4*)(dst + 8) = v1;
  }

  // ---- threefry dropout-mask phase (fills VALU pipe chip-wide) ----
  const uint32 wbeg = (uint32)(blockIdx.y * 66 + blockIdx.x) * MWPB_;
  for (uint32 wI = wbeg + (uint32)tid; wI < wbeg + MWPB_; wI += 256u) {
    const uint32 rowIdx = wI / WPR_;
    const uint32 jw = wI - rowIdx * WPR_;
    const uint32 bI = rowIdx / (NH_ * T_);
    const uint32 rem = rowIdx - bI * (NH_ * T_);
    const uint32 iQ = rem % T_;
    const uint32 c0 = bI * HALF_U + rem * (uint32)T_ + jw * 32u;
    const uint32 thr = ((iQ < NX_) && (jw < 64u)) ? K_X_ : K_LQ_;
    uint32 word = 0u;
#pragma unroll 4
    for (int k = 0; k < 32; ++k) {
      const uint2 y = threefry_(0u, c0 + (uint32)k);
      word |= (((y.x ^ y.y) >> 9) < thr ? 1u : 0u) << k;
    }
    Mask[wI] = word;
  }
}

// ---------- MFMA flash attention, reads precomputed mask ----------
__global__ __launch_bounds__(128) void attn_kernel(
    const unsigned short* __restrict__ Qh, const unsigned short* __restrict__ Kh,
    const unsigned short* __restrict__ Vth, const uint32* __restrict__ Mask,
    float* __restrict__ ctx) {
  __shared__ unsigned short KsU[4096];
  __shared__ unsigned short VsU[4096];
  __shared__ unsigned short PsU[2 * 1152];
  const int tid = threadIdx.x;
  const int w = tid >> 6;          // 2 waves
  const int lane = tid & 63;
  const int c = lane & 15;
  const int g = lane >> 4;
  const int q0 = blockIdx.x << 5;  // 32 q-rows/block
  const int h = blockIdx.y;
  const int b = blockIdx.z;
  const size_t hbT = (size_t)(b * NH_ + h) * T_;
  const size_t vbase = (size_t)(b * NH_ + h) * HD_;

  bf16x8 aq0, aq1;
  {
    const unsigned short* qrow = Qh + (hbT + q0 + 16 * w + c) * HD_ + (g << 3);
    aq0 = *(const bf16x8*)(qrow);
    aq1 = *(const bf16x8*)(qrow + 32);
  }
  f32x4 ca0 = {0.f, 0.f, 0.f, 0.f}, ca1 = ca0, ca2 = ca0, ca3 = ca0;
  float lacc[4] = {0.f, 0.f, 0.f, 0.f};
  uint32 wb[4];
#pragma unroll
  for (int i = 0; i < 4; ++i)
    wb[i] = ((uint32)b * HALF_U +
             (uint32)(h * T_ + q0 + 16 * w + 4 * g + i) * (uint32)T_) >> 5;  // row base %32==0

  const int psE = w * 1152;
  const int psB = w * 2304;
  const int swz = (c & 7) << 4;

  for (int kt = 0; kt < T_; kt += 64) {
#pragma unroll
    for (int ii = 0; ii < 4; ++ii) {
      const int seg = tid + (ii << 7);
      const int srow = seg >> 3;
      const int sc = (seg & 7) << 3;
      const uint4 kv4 = *(const uint4*)(Kh + (hbT + kt + srow) * HD_ + sc);
      *(uint4*)((char*)KsU + srow * 128 + ((sc * 2) ^ ((srow & 7) << 4))) = kv4;
      const uint4 vv4 = *(const uint4*)(Vth + (vbase + srow) * T_ + kt + sc);
      *(uint4*)((char*)VsU + srow * 128 + ((sc * 2) ^ ((srow & 7) << 4))) = vv4;
    }
    __syncthreads();

    f32x4 sa0 = {0.f, 0.f, 0.f, 0.f}, sa1 = sa0, sa2 = sa0, sa3 = sa0;
#pragma unroll
    for (int s = 0; s < 2; ++s) {
      const int off = ((s << 6) | (g << 4)) ^ swz;
      const bf16x8 bk0 = *(const bf16x8*)((const char*)KsU + (c) * 128 + off);
      const bf16x8 bk1 = *(const bf16x8*)((const char*)KsU + (c + 16) * 128 + off);
      const bf16x8 bk2 = *(const bf16x8*)((const char*)KsU + (c + 32) * 128 + off);
      const bf16x8 bk3 = *(const bf16x8*)((const char*)KsU + (c + 48) * 128 + off);
      const bf16x8 aqs = s ? aq1 : aq0;
      sa0 = __builtin_amdgcn_mfma_f32_16x16x32_bf16(aqs, bk0, sa0, 0, 0, 0);
      sa1 = __builtin_amdgcn_mfma_f32_16x16x32_bf16(aqs, bk1, sa1, 0, 0, 0);
      sa2 = __builtin_amdgcn_mfma_f32_16x16x32_bf16(aqs, bk2, sa2, 0, 0, 0);
      sa3 = __builtin_amdgcn_mfma_f32_16x16x32_bf16(aqs, bk3, sa3, 0, 0, 0);
    }

    const uint32 ktw = (uint32)(kt >> 5);
#pragma unroll
    for (int n = 0; n < 4; ++n) {
      const f32x4 sv = (n == 0) ? sa0 : (n == 1) ? sa1 : (n == 2) ? sa2 : sa3;
      const int sh = ((n & 1) << 4) + c;
      const uint32 wOff = ktw + (n >> 1);
#pragma unroll
      for (int i = 0; i < 4; ++i) {
        const float pe = __expf(sv[i]);
        lacc[i] += pe;
        const uint32 word = Mask[wb[i] + wOff];
        PsU[psE + (4 * g + i) * 72 + 16 * n + c] =
            ((word >> sh) & 1u) ? f2b_(pe) : (unsigned short)0;
      }
    }
    __syncthreads();

    const bf16x8 ap0 = *(const bf16x8*)((const char*)PsU + psB + c * 144 + (g << 4));
    const bf16x8 ap1 = *(const bf16x8*)((const char*)PsU + psB + c * 144 + 64 + (g << 4));
#pragma unroll
    for (int s = 0; s < 2; ++s) {
      const int off = ((s << 6) | (g << 4)) ^ swz;
      const bf16x8 bv0 = *(const bf16x8*)((const char*)VsU + (c) * 128 + off);
      const bf16x8 bv1 = *(const bf16x8*)((const char*)VsU + (c + 16) * 128 + off);
      const bf16x8 bv2 = *(const bf16x8*)((const char*)VsU + (c + 32) * 128 + off);
      const bf16x8 bv3 = *(const bf16x8*)((const char*)VsU + (c + 48) * 128 + off);
      const bf16x8 aps = s ? ap1 : ap0;
      ca0 = __builtin_amdgcn_mfma_f32_16x16x32_bf16(aps, bv0, ca0, 0, 0, 0);
      ca1 = __builtin_amdgcn_mfma_f32_16x16x32_bf16(aps, bv1, ca1, 0, 0, 0);
      ca2 = __builtin_amdgcn_mfma_f32_16x16x32_bf16(aps, bv2, ca2, 0, 0, 0);
      ca3 = __builtin_amdgcn_mfma_f32_16x16x32_bf16(aps, bv3, ca3, 0, 0, 0);
    }
    __syncthreads();
  }

#pragma unroll
  for (int i = 0; i < 4; ++i) {
    float li = lacc[i];
    li += __shfl_xor(li, 1);
    li += __shfl_xor(li, 2);
    li += __shfl_xor(li, 4);
    li += __shfl_xor(li, 8);
    const float inv = SCALE_ / li;
    float* dst = ctx + (size_t)(b * T_ + q0 + 16 * w + 4 * g + i) * DOUT_ + (h << 6) + c;
    dst[0]  = ca0[i] * inv;
    dst[16] = ca1[i] * inv;
    dst[32] = ca2[i] * inv;
    dst[48] = ca3[i] * inv;
  }
}

// ---------- oproj: bf16 MFMA GEMM + bias ----------
__global__ __launch_bounds__(256) void oproj_kernel(
    const float* __restrict__ ctxm, const unsigned short* __restrict__ Wt,
    const float* __restrict__ bo, float* __restrict__ out) {
  __shared__ unsigned short AsB[4096];
  __shared__ unsigned short BsB[4096];
  const int tid = threadIdx.x;
  const int w = tid >> 6;
  const int lane = tid & 63;
  const int c = lane & 15;
  const int g = lane >> 4;
  const int m0 = blockIdx.x << 6;
  const int n0 = blockIdx.y << 6;
  const int ar = tid >> 2;
  const int kpart = (tid & 3) << 4;
  const float* arow = ctxm + (size_t)(m0 + ar) * DIN_;
  const unsigned short* brow = Wt + ((size_t)3 * DOUT_ + n0 + ar) * DIN_;
  const int wrA = ar * 128;
  const int swzS = (ar & 7) << 4;
  const int swzF = (c & 7) << 4;

  f32x4 ac0 = {0.f, 0.f, 0.f, 0.f}, ac1 = ac0, ac2 = ac0, ac3 = ac0;
  for (int k0 = 0; k0 < DIN_; k0 += 64) {
    const float4 a0 = *(const float4*)(arow + k0 + kpart);
    const float4 a1 = *(const float4*)(arow + k0 + kpart + 4);
    const float4 a2 = *(const float4*)(arow + k0 + kpart + 8);
    const float4 a3 = *(const float4*)(arow + k0 + kpart + 12);
    const uint4 b01 = *(const uint4*)(brow + k0 + kpart);
    const uint4 b23 = *(const uint4*)(brow + k0 + kpart + 8);
    uint4 pa0, pa1;
    pa0.x = pack2_(a0.x, a0.y); pa0.y = pack2_(a0.z, a0.w);
    pa0.z = pack2_(a1.x, a1.y); pa0.w = pack2_(a1.z, a1.w);
    pa1.x = pack2_(a2.x, a2.y); pa1.y = pack2_(a2.z, a2.w);
    pa1.z = pack2_(a3.x, a3.y); pa1.w = pack2_(a3.z, a3.w);
    __syncthreads();
    *(uint4*)((char*)AsB + wrA + ((kpart * 2) ^ swzS)) = pa0;
    *(uint4*)((char*)AsB + wrA + ((kpart * 2 + 16) ^ swzS)) = pa1;
    *(uint4*)((char*)BsB + wrA + ((kpart * 2) ^ swzS)) = b01;
    *(uint4*)((char*)BsB + wrA + ((kpart * 2 + 16) ^ swzS)) = b23;
    __syncthreads();
#pragma unroll
    for (int s = 0; s < 2; ++s) {
      const int off = ((s << 6) | (g << 4)) ^ swzF;
      const bf16x8 af = *(const bf16x8*)((const char*)AsB + (16 * w + c) * 128 + off);
      const bf16x8 b0 = *(const bf16x8*)((const char*)BsB + (c) * 128 + off);
      const bf16x8 b1 = *(const bf16x8*)((const char*)BsB + (c + 16) * 128 + off);
      const bf16x8 b2 = *(const bf16x8*)((const char*)BsB + (c + 32) * 128 + off);
      const bf16x8 b3 = *(const bf16x8*)((const char*)BsB + (c + 48) * 128 + off);
      ac0 = __builtin_amdgcn_mfma_f32_16x16x32_bf16(af, b0, ac0, 0, 0, 0);
      ac1 = __builtin_amdgcn_mfma_f32_16x16x32_bf16(af, b1, ac1, 0, 0, 0);
      ac2 = __builtin_amdgcn_mfma_f32_16x16x32_bf16(af, b2, ac2, 0, 0, 0);
      ac3 = __builtin_amdgcn_mfma_f32_16x16x32_bf16(af, b3, ac3, 0, 0, 0);
    }
  }
  const float bi0 = bo[n0 + c];
  const float bi1 = bo[n0 + 16 + c];
  const float bi2 = bo[n0 + 32 + c];
  const float bi3 = bo[n0 + 48 + c];
#pragma unroll
  for (int i = 0; i < 4; ++i) {
    float* dst = out + (size_t)(m0 + 16 * w + 4 * g + i) * DOUT_ + n0 + c;
    dst[0]  = ac0[i] + bi0;
    dst[16] = ac1[i] + bi1;
    dst[32] = ac2[i] + bi2;
    dst[48] = ac3[i] + bi3;
  }
}

extern "C" void kernel_launch(void* const* d_in, const int* in_sizes, int n_in,
                              void* d_out, int out_size, void* d_ws, size_t ws_size,
                              hipStream_t stream) {
  (void)in_sizes; (void)n_in; (void)out_size; (void)ws_size;
  const float* x  = (const float*)d_in[0];
  const float* lq = (const float*)d_in[1];
  const float* Wq = (const float*)d_in[2];
  const float* Wk = (const float*)d_in[3];
  const float* Wv = (const float*)d_in[4];
  const float* Wo = (const float*)d_in[5];
  const float* bo = (const float*)d_in[6];
  unsigned short* Qh  = (unsigned short*)d_ws;
  unsigned short* Kh  = Qh + QSZ_;
  unsigned short* Vth = Kh + QSZ_;
  float* Cb = (float*)(Vth + QSZ_);                       // 19.46 MB offset
  unsigned short* Wt = (unsigned short*)(Cb + QSZ_);      // 32.44 MB offset, 4.72 MB
  uint32* Mask = (uint32*)((char*)d_ws + 37158912);       // 13.38 MB -> ends 50.5 MB
  prep_kernel<<<dim3(12, 12, 4), dim3(256), 0, stream>>>(Wq, Wk, Wv, Wo, Wt);
  qkv_kernel<<<dim3(66, 36), dim3(256), 0, stream>>>(x, lq, Wt, Qh, Kh, Vth, Mask);
  attn_kernel<<<dim3(66, NH_, B_), dim3(128), 0, stream>>>(Qh, Kh, Vth, Mask, Cb);
  oproj_kernel<<<dim3(66, 12), dim3(256), 0, stream>>>(Cb, Wt, bo, (float*)d_out);
}